// Round 2
// baseline (2320.340 us; speedup 1.0000x reference)
//
#include <hip/hip_runtime.h>
#include <hip/hip_bf16.h>
#include <hip/hip_cooperative_groups.h>
#include <math.h>

namespace cg = cooperative_groups;

typedef __bf16 bf16x8 __attribute__((ext_vector_type(8)));
typedef float  f32x4  __attribute__((ext_vector_type(4)));

#define HDIM   512
#define FLAT   65792
#define DIN    66304
#define G3     1536          // 3*H
#define NSLAB  2056          // FLAT / 32
#define NPAD   544           // padded GEMM N: 512 (M) + 1 (b_proj) + 1 (start) + 30 zero
#define LPITCH 40            // LDS row pitch in ushorts (80 B -> 2-way-free banks)
#define MT     128           // GEMM M tile
#define KSPLIT 21
#define CHUNK  98            // slabs per K chunk (21*98 >= 2056)

#define BH_BYTES  71581696ULL
#define MBUF_BYTES 3342336ULL   // G3*NPAD*4
#define GIB_BYTES   393216ULL   // 64*G3*4
#define HALL_BYTES  131072ULL   // 64*512*4
#define HBF_BYTES    65536ULL   // 64*512*2

__device__ __forceinline__ ushort f2bf(float f) {
    uint u = __float_as_uint(f);
    u += 0x7FFFu + ((u >> 16) & 1u);   // round-to-nearest-even
    return (ushort)(u >> 16);
}

// ---------------------------------------------------------------------------
// K1 (fast path): build blocked bf16 B matrix for the big GEMM.
// ---------------------------------------------------------------------------
__global__ __launch_bounds__(256) void buildBh(const float* __restrict__ Wp,
                                               const float* __restrict__ bproj,
                                               const float* __restrict__ start,
                                               ushort* __restrict__ Bh) {
    __shared__ ushort tr[512 * 33];
    const int slab = blockIdx.x;
    const int tid  = threadIdx.x;
    for (int idx = tid; idx < 32 * 512; idx += 256) {
        const int k = idx >> 9;
        const int n = idx & 511;
        tr[n * 33 + k] = f2bf(Wp[(size_t)(slab * 32 + k) * 512 + n]);
    }
    __syncthreads();
    uint* out = (uint*)(Bh + (size_t)slab * 17408);
    for (int d = tid; d < 8704; d += 256) {
        const int n  = d >> 4;
        const int k2 = (d & 15) * 2;
        ushort lo, hi;
        if (n < 512)      { lo = tr[n * 33 + k2];            hi = tr[n * 33 + k2 + 1]; }
        else if (n == 512){ lo = f2bf(bproj[slab * 32 + k2]); hi = f2bf(bproj[slab * 32 + k2 + 1]); }
        else if (n == 513){ lo = f2bf(start[slab * 32 + k2]); hi = f2bf(start[slab * 32 + k2 + 1]); }
        else              { lo = 0; hi = 0; }
        out[d] = (uint)lo | ((uint)hi << 16);
    }
}

// ---------------------------------------------------------------------------
// K2 (fast path): M = W_ih[:,512:] @ [W_proj | b_proj | start | 0pad] (1536x544)
// ---------------------------------------------------------------------------
__global__ __launch_bounds__(1024) void gemmM(const float* __restrict__ Wih,
                                              const ushort* __restrict__ Bh,
                                              float* __restrict__ Mbuf) {
    __shared__ ushort Alds[MT * LPITCH];     // 10240 B
    __shared__ ushort Blds[NPAD * LPITCH];   // 43520 B
    const int tid  = threadIdx.x;
    const int lane = tid & 63;
    const int wave = tid >> 6;
    const int wm   = wave >> 1;       // 0..7  -> rows wm*16
    const int wn   = wave & 1;        // 0..1  -> cols wn*272
    const int lrow = lane & 15;
    const int quad = lane >> 4;
    const int bid   = blockIdx.x;
    const int mtile = bid % 12;
    const int kc    = bid / 12;
    const int s0 = kc * CHUNK;
    const int s1 = min(s0 + CHUNK, NSLAB);

    const int arow = tid >> 3;
    const int aseg = tid & 7;
    const float* aPtr = Wih + (size_t)(mtile * MT + arow) * DIN + 512 + aseg * 4;

    f32x4 acc[17];
#pragma unroll
    for (int t = 0; t < 17; ++t) acc[t] = (f32x4){0.f, 0.f, 0.f, 0.f};

    float4 aReg;
    uint4  bReg0 = {}, bReg1 = {}, bReg2 = {};
    {
        const size_t sb = (size_t)s0 * 17408;
        aReg  = *(const float4*)(aPtr + (size_t)s0 * 32);
        bReg0 = *(const uint4*)(Bh + sb + (size_t)tid * 8);
        bReg1 = *(const uint4*)(Bh + sb + (size_t)(tid + 1024) * 8);
        if (tid < 128) bReg2 = *(const uint4*)(Bh + sb + (size_t)(tid + 2048) * 8);
    }
    for (int s = s0; s < s1; ++s) {
        {
            uint2 ap;
            ap.x = (uint)f2bf(aReg.x) | ((uint)f2bf(aReg.y) << 16);
            ap.y = (uint)f2bf(aReg.z) | ((uint)f2bf(aReg.w) << 16);
            *(uint2*)&Alds[arow * LPITCH + aseg * 4] = ap;
            *(uint4*)&Blds[(tid >> 2) * LPITCH + (tid & 3) * 8] = bReg0;
            const int c1 = tid + 1024;
            *(uint4*)&Blds[(c1 >> 2) * LPITCH + (c1 & 3) * 8] = bReg1;
            if (tid < 128) {
                const int c2 = tid + 2048;
                *(uint4*)&Blds[(c2 >> 2) * LPITCH + (c2 & 3) * 8] = bReg2;
            }
        }
        __syncthreads();
        if (s + 1 < s1) {
            const size_t sb = (size_t)(s + 1) * 17408;
            aReg  = *(const float4*)(aPtr + (size_t)(s + 1) * 32);
            bReg0 = *(const uint4*)(Bh + sb + (size_t)tid * 8);
            bReg1 = *(const uint4*)(Bh + sb + (size_t)(tid + 1024) * 8);
            if (tid < 128) bReg2 = *(const uint4*)(Bh + sb + (size_t)(tid + 2048) * 8);
        }
        const bf16x8 af = __builtin_bit_cast(bf16x8,
            *(const uint4*)&Alds[(wm * 16 + lrow) * LPITCH + quad * 8]);
#pragma unroll
        for (int t = 0; t < 17; ++t) {
            const bf16x8 bf = __builtin_bit_cast(bf16x8,
                *(const uint4*)&Blds[(wn * 272 + t * 16 + lrow) * LPITCH + quad * 8]);
            acc[t] = __builtin_amdgcn_mfma_f32_16x16x32_bf16(af, bf, acc[t], 0, 0, 0);
        }
        __syncthreads();
    }
#pragma unroll
    for (int t = 0; t < 17; ++t) {
        const int col = wn * 272 + t * 16 + lrow;
#pragma unroll
        for (int r = 0; r < 4; ++r) {
            const int row = mtile * MT + wm * 16 + quad * 4 + r;
            atomicAdd(&Mbuf[(size_t)row * NPAD + col], acc[t][r]);
        }
    }
}

// ---------------------------------------------------------------------------
// K2' (fallback, small ws_size)
// ---------------------------------------------------------------------------
__global__ __launch_bounds__(1024) void gemmMDirect(const float* __restrict__ Wih,
                                                    const float* __restrict__ Wp,
                                                    const float* __restrict__ bproj,
                                                    const float* __restrict__ start,
                                                    float* __restrict__ Mbuf) {
    __shared__ ushort Alds[MT * LPITCH];
    __shared__ ushort Blds[NPAD * LPITCH];
    const int tid  = threadIdx.x;
    const int lane = tid & 63;
    const int wave = tid >> 6;
    const int wm   = wave >> 1;
    const int wn   = wave & 1;
    const int lrow = lane & 15;
    const int quad = lane >> 4;
    const int bid   = blockIdx.x;
    const int mtile = bid % 12;
    const int kc    = bid / 12;
    const int s0 = kc * CHUNK;
    const int s1 = min(s0 + CHUNK, NSLAB);

    const int arow = tid >> 3;
    const int aseg = tid & 7;
    const float* aPtr = Wih + (size_t)(mtile * MT + arow) * DIN + 512 + aseg * 4;

    const int bk = tid >> 5;
    const int bn0 = (tid & 31) * 4;
    const int ek = tid & 31;
    const float* esrc = (tid < 32) ? bproj : start;

    for (int idx = tid; idx < 30 * LPITCH; idx += 1024) Blds[514 * LPITCH + idx] = 0;

    f32x4 acc[17];
#pragma unroll
    for (int t = 0; t < 17; ++t) acc[t] = (f32x4){0.f, 0.f, 0.f, 0.f};

    float4 aReg;
    float4 bReg[4];
    float  eReg = 0.f;
    {
        aReg = *(const float4*)(aPtr + (size_t)s0 * 32);
        const float* bbase = Wp + (size_t)(s0 * 32 + bk) * 512 + bn0;
#pragma unroll
        for (int q = 0; q < 4; ++q) bReg[q] = *(const float4*)(bbase + q * 128);
        if (tid < 64) eReg = esrc[s0 * 32 + ek];
    }
    for (int s = s0; s < s1; ++s) {
        {
            uint2 ap;
            ap.x = (uint)f2bf(aReg.x) | ((uint)f2bf(aReg.y) << 16);
            ap.y = (uint)f2bf(aReg.z) | ((uint)f2bf(aReg.w) << 16);
            *(uint2*)&Alds[arow * LPITCH + aseg * 4] = ap;
#pragma unroll
            for (int q = 0; q < 4; ++q) {
                const int n = bn0 + q * 128;
                Blds[(n + 0) * LPITCH + bk] = f2bf(bReg[q].x);
                Blds[(n + 1) * LPITCH + bk] = f2bf(bReg[q].y);
                Blds[(n + 2) * LPITCH + bk] = f2bf(bReg[q].z);
                Blds[(n + 3) * LPITCH + bk] = f2bf(bReg[q].w);
            }
            if (tid < 64) Blds[(512 + (tid >> 5)) * LPITCH + ek] = f2bf(eReg);
        }
        __syncthreads();
        if (s + 1 < s1) {
            aReg = *(const float4*)(aPtr + (size_t)(s + 1) * 32);
            const float* bbase = Wp + (size_t)((s + 1) * 32 + bk) * 512 + bn0;
#pragma unroll
            for (int q = 0; q < 4; ++q) bReg[q] = *(const float4*)(bbase + q * 128);
            if (tid < 64) eReg = esrc[(s + 1) * 32 + ek];
        }
        const bf16x8 af = __builtin_bit_cast(bf16x8,
            *(const uint4*)&Alds[(wm * 16 + lrow) * LPITCH + quad * 8]);
#pragma unroll
        for (int t = 0; t < 17; ++t) {
            const bf16x8 bf = __builtin_bit_cast(bf16x8,
                *(const uint4*)&Blds[(wn * 272 + t * 16 + lrow) * LPITCH + quad * 8]);
            acc[t] = __builtin_amdgcn_mfma_f32_16x16x32_bf16(af, bf, acc[t], 0, 0, 0);
        }
        __syncthreads();
    }
#pragma unroll
    for (int t = 0; t < 17; ++t) {
        const int col = wn * 272 + t * 16 + lrow;
#pragma unroll
        for (int r = 0; r < 4; ++r) {
            const int row = mtile * MT + wm * 16 + quad * 4 + r;
            atomicAdd(&Mbuf[(size_t)row * NPAD + col], acc[t][r]);
        }
    }
}

// ---------------------------------------------------------------------------
// K3: gi_base
// ---------------------------------------------------------------------------
__global__ __launch_bounds__(256) void giBase(const float* __restrict__ Wih,
                                              const float* __restrict__ content,
                                              const float* __restrict__ style,
                                              const float* __restrict__ bih,
                                              const float* __restrict__ Mbuf,
                                              float* __restrict__ giB) {
    const int j = (blockIdx.x * blockDim.x + threadIdx.x) >> 6;
    if (j >= G3) return;
    const int lane = threadIdx.x & 63;   // pair = b*16 + s
    const int b = lane >> 4;
    const int s = lane & 15;
    const float* wr = Wih + (size_t)j * DIN;
    const float* cp = content + (size_t)lane * 256;
    const float* sp = style + (size_t)b * 256;
    float acc = 0.f;
#pragma unroll 4
    for (int d = 0; d < 256; d += 4) {
        const float4 w = *(const float4*)(wr + d);
        const float4 x = *(const float4*)(cp + d);
        acc += w.x * x.x + w.y * x.y + w.z * x.z + w.w * x.w;
    }
#pragma unroll 4
    for (int d = 0; d < 256; d += 4) {
        const float4 w = *(const float4*)(wr + 256 + d);
        const float4 x = *(const float4*)(sp + d);
        acc += w.x * x.x + w.y * x.y + w.z * x.z + w.w * x.w;
    }
    acc += bih[j] + ((s == 0) ? Mbuf[(size_t)j * NPAD + 513] : Mbuf[(size_t)j * NPAD + 512]);
    giB[(size_t)lane * G3 + j] = acc;
}

// ---------------------------------------------------------------------------
// K4 fused: all 16 GRU steps in one cooperative kernel, grid.sync between
// steps. Weight rows (6 x 512 per wave-task) are step-invariant -> preloaded
// into 48 VGPRs once; per step only h (8 loads) + FMAs + shuffle reduce.
// ---------------------------------------------------------------------------
__global__ __launch_bounds__(256) void stepsFused(const float* __restrict__ Mbuf,
                                                  const float* __restrict__ Whh,
                                                  const float* __restrict__ bhh,
                                                  const float* __restrict__ giB,
                                                  float* __restrict__ hAll,
                                                  ushort* __restrict__ hBf) {
    cg::grid_group grid = cg::this_grid();
    const int gw   = (blockIdx.x * blockDim.x + threadIdx.x) >> 6;  // 0..2047
    const int lane = threadIdx.x & 63;
    const int b = gw & 3;
    const int j = gw >> 2;          // 0..511

    const float* M0 = Mbuf + (size_t)j * NPAD;
    const float* M1 = Mbuf + (size_t)(j + 512) * NPAD;
    const float* M2 = Mbuf + (size_t)(j + 1024) * NPAD;
    const float* W0 = Whh + (size_t)j * HDIM;
    const float* W1 = Whh + (size_t)(j + 512) * HDIM;
    const float* W2 = Whh + (size_t)(j + 1024) * HDIM;
    float m0[8], m1[8], m2[8], w0[8], w1[8], w2[8];
#pragma unroll
    for (int i = 0; i < 8; ++i) {
        const int d = i * 64 + lane;
        m0[i] = M0[d]; m1[i] = M1[d]; m2[i] = M2[d];
        w0[i] = W0[d]; w1[i] = W1[d]; w2[i] = W2[d];
    }
    const float bh0 = bhh[j], bh1 = bhh[j + 512], bh2 = bhh[j + 1024];

    for (int s = 0; s < 16; ++s) {
        float dMr = 0.f, dMz = 0.f, dMn = 0.f, dWr = 0.f, dWz = 0.f, dWn = 0.f;
        if (s > 0) {
            const float* h = hAll + (size_t)((s - 1) * 4 + b) * HDIM;
            float hr[8];
#pragma unroll
            for (int i = 0; i < 8; ++i) hr[i] = h[i * 64 + lane];
#pragma unroll
            for (int i = 0; i < 8; ++i) {
                dMr += m0[i] * hr[i]; dMz += m1[i] * hr[i]; dMn += m2[i] * hr[i];
                dWr += w0[i] * hr[i]; dWz += w1[i] * hr[i]; dWn += w2[i] * hr[i];
            }
#pragma unroll
            for (int m = 1; m < 64; m <<= 1) {
                dMr += __shfl_xor(dMr, m); dMz += __shfl_xor(dMz, m); dMn += __shfl_xor(dMn, m);
                dWr += __shfl_xor(dWr, m); dWz += __shfl_xor(dWz, m); dWn += __shfl_xor(dWn, m);
            }
        }
        if (lane == 0) {
            const float* gb = giB + (size_t)(b * 16 + s) * G3;
            const float gir = gb[j] + dMr;
            const float giz = gb[j + 512] + dMz;
            const float gin = gb[j + 1024] + dMn;
            const float r = 1.f / (1.f + expf(-(gir + bh0 + dWr)));
            const float z = 1.f / (1.f + expf(-(giz + bh1 + dWz)));
            const float n = tanhf(gin + r * (bh2 + dWn));
            const float hp = (s > 0) ? hAll[(size_t)((s - 1) * 4 + b) * HDIM + j] : 0.f;
            const float hn = (1.f - z) * n + z * hp;
            hAll[(size_t)(s * 4 + b) * HDIM + j] = hn;
            hBf[(size_t)(s * 4 + b) * HDIM + j] = f2bf(hn);
        }
        __threadfence();     // make lane0's h stores device-visible before sync
        grid.sync();
    }
}

// ---------------------------------------------------------------------------
// K4' (fallback if cooperative launch unavailable): one GRU step per launch.
// ---------------------------------------------------------------------------
__global__ __launch_bounds__(256) void stepK(const float* __restrict__ Mbuf,
                                             const float* __restrict__ Whh,
                                             const float* __restrict__ bhh,
                                             const float* __restrict__ giB,
                                             float* __restrict__ hAll,
                                             ushort* __restrict__ hBf,
                                             const int s) {
    const int gw   = (blockIdx.x * blockDim.x + threadIdx.x) >> 6;  // 0..2047
    const int lane = threadIdx.x & 63;
    const int b = gw & 3;
    const int j = gw >> 2;          // 0..511
    float dMr = 0.f, dMz = 0.f, dMn = 0.f, dWr = 0.f, dWz = 0.f, dWn = 0.f;
    if (s > 0) {
        const float* h = hAll + (size_t)((s - 1) * 4 + b) * HDIM;
        float hr[8];
#pragma unroll
        for (int i = 0; i < 8; ++i) hr[i] = h[i * 64 + lane];
        const float* M0 = Mbuf + (size_t)j * NPAD;
        const float* M1 = Mbuf + (size_t)(j + 512) * NPAD;
        const float* M2 = Mbuf + (size_t)(j + 1024) * NPAD;
        const float* W0 = Whh + (size_t)j * HDIM;
        const float* W1 = Whh + (size_t)(j + 512) * HDIM;
        const float* W2 = Whh + (size_t)(j + 1024) * HDIM;
#pragma unroll
        for (int i = 0; i < 8; ++i) {
            const int d = i * 64 + lane;
            dMr += M0[d] * hr[i]; dMz += M1[d] * hr[i]; dMn += M2[d] * hr[i];
            dWr += W0[d] * hr[i]; dWz += W1[d] * hr[i]; dWn += W2[d] * hr[i];
        }
#pragma unroll
        for (int m = 1; m < 64; m <<= 1) {
            dMr += __shfl_xor(dMr, m); dMz += __shfl_xor(dMz, m); dMn += __shfl_xor(dMn, m);
            dWr += __shfl_xor(dWr, m); dWz += __shfl_xor(dWz, m); dWn += __shfl_xor(dWn, m);
        }
    }
    if (lane == 0) {
        const float* gb = giB + (size_t)(b * 16 + s) * G3;
        const float gir = gb[j] + dMr;
        const float giz = gb[j + 512] + dMz;
        const float gin = gb[j + 1024] + dMn;
        const float ghr = bhh[j] + dWr;
        const float ghz = bhh[j + 512] + dWz;
        const float ghn = bhh[j + 1024] + dWn;
        const float r = 1.f / (1.f + expf(-(gir + ghr)));
        const float z = 1.f / (1.f + expf(-(giz + ghz)));
        const float n = tanhf(gin + r * ghn);
        const float hp = (s > 0) ? hAll[(size_t)((s - 1) * 4 + b) * HDIM + j] : 0.f;
        const float hn = (1.f - z) * n + z * hp;
        hAll[(size_t)(s * 4 + b) * HDIM + j] = hn;
        hBf[(size_t)(s * 4 + b) * HDIM + j] = f2bf(hn);
    }
}

// ---------------------------------------------------------------------------
// K5: out[b][s][f] = W_proj[f] . h[s*4+b] + b_proj[f], MFMA bf16.
// ---------------------------------------------------------------------------
__global__ __launch_bounds__(256) void projK(const float* __restrict__ Wp,
                                             const float* __restrict__ bproj,
                                             const ushort* __restrict__ hBf,
                                             float* __restrict__ out) {
    const int lane = threadIdx.x & 63;
    const int wave = threadIdx.x >> 6;
    const int f0   = blockIdx.x * 256 + wave * 64;
    const int lrow = lane & 15;
    const int quad = lane >> 4;
    f32x4 acc[4][4];
#pragma unroll
    for (int pt = 0; pt < 4; ++pt)
#pragma unroll
        for (int ft = 0; ft < 4; ++ft) acc[pt][ft] = (f32x4){0.f, 0.f, 0.f, 0.f};

    for (int d0 = 0; d0 < HDIM; d0 += 32) {
        bf16x8 afr[4];
#pragma unroll
        for (int pt = 0; pt < 4; ++pt)
            afr[pt] = __builtin_bit_cast(bf16x8,
                *(const uint4*)(hBf + (size_t)(pt * 16 + lrow) * HDIM + d0 + quad * 8));
#pragma unroll
        for (int ft = 0; ft < 4; ++ft) {
            const float* wrow = Wp + (size_t)(f0 + ft * 16 + lrow) * HDIM + d0 + quad * 8;
            const float4 w0 = *(const float4*)(wrow);
            const float4 w1 = *(const float4*)(wrow + 4);
            uint4 pr;
            pr.x = (uint)f2bf(w0.x) | ((uint)f2bf(w0.y) << 16);
            pr.y = (uint)f2bf(w0.z) | ((uint)f2bf(w0.w) << 16);
            pr.z = (uint)f2bf(w1.x) | ((uint)f2bf(w1.y) << 16);
            pr.w = (uint)f2bf(w1.z) | ((uint)f2bf(w1.w) << 16);
            const bf16x8 bfr = __builtin_bit_cast(bf16x8, pr);
#pragma unroll
            for (int pt = 0; pt < 4; ++pt)
                acc[pt][ft] = __builtin_amdgcn_mfma_f32_16x16x32_bf16(afr[pt], bfr, acc[pt][ft], 0, 0, 0);
        }
    }
#pragma unroll
    for (int pt = 0; pt < 4; ++pt)
#pragma unroll
        for (int ft = 0; ft < 4; ++ft) {
            const int f = f0 + ft * 16 + lrow;
            const float bp = bproj[f];
#pragma unroll
            for (int r = 0; r < 4; ++r) {
                const int p = pt * 16 + quad * 4 + r;   // pair index = s*4 + b
                const int ss = p >> 2;
                const int bb = p & 3;
                out[(size_t)(bb * 16 + ss) * FLAT + f] = acc[pt][ft][r] + bp;
            }
        }
}

// ---------------------------------------------------------------------------
extern "C" void kernel_launch(void* const* d_in, const int* in_sizes, int n_in,
                              void* d_out, int out_size, void* d_ws, size_t ws_size,
                              hipStream_t stream) {
    const float* content = (const float*)d_in[0];  // (4,16,256)
    const float* style   = (const float*)d_in[1];  // (4,256)
    const float* start   = (const float*)d_in[2];  // (65792)
    const float* Wih     = (const float*)d_in[3];  // (1536, 66304)
    const float* Whh     = (const float*)d_in[4];  // (1536, 512)
    const float* bih     = (const float*)d_in[5];  // (1536)
    const float* bhh     = (const float*)d_in[6];  // (1536)
    const float* Wproj   = (const float*)d_in[7];  // (65792, 512)
    const float* bproj   = (const float*)d_in[8];  // (65792)
    float* out = (float*)d_out;

    const size_t needFast = BH_BYTES + MBUF_BYTES + GIB_BYTES + HALL_BYTES + HBF_BYTES;
    const bool fast = (ws_size >= needFast);   // constant per deployment -> graph-safe

    char* ws = (char*)d_ws;
    const size_t base = fast ? BH_BYTES : 0;
    ushort* Bh   = (ushort*)ws;
    float*  Mbuf = (float*)(ws + base);
    float*  giB  = (float*)(ws + base + MBUF_BYTES);
    float*  hAll = (float*)(ws + base + MBUF_BYTES + GIB_BYTES);
    ushort* hBf  = (ushort*)(ws + base + MBUF_BYTES + GIB_BYTES + HALL_BYTES);

    hipMemsetAsync(Mbuf, 0, MBUF_BYTES, stream);
    if (fast) {
        buildBh<<<NSLAB, 256, 0, stream>>>(Wproj, bproj, start, Bh);
        gemmM<<<12 * KSPLIT, 1024, 0, stream>>>(Wih, Bh, Mbuf);
    } else {
        gemmMDirect<<<12 * KSPLIT, 1024, 0, stream>>>(Wih, Wproj, bproj, start, Mbuf);
    }
    giBase<<<384, 256, 0, stream>>>(Wih, content, style, bih, Mbuf, giB);

    // Fused 16-step GRU via cooperative launch (512 blocks = 2/CU, co-resident).
    {
        const float* MbufC = Mbuf;
        const float* giBC  = giB;
        void* args[] = { (void*)&MbufC, (void*)&Whh, (void*)&bhh,
                         (void*)&giBC, (void*)&hAll, (void*)&hBf };
        hipError_t e = hipLaunchCooperativeKernel((const void*)stepsFused,
                                                  dim3(512), dim3(256), args, 0, stream);
        if (e != hipSuccess) {
            for (int s = 0; s < 16; ++s)
                stepK<<<512, 256, 0, stream>>>(Mbuf, Whh, bhh, giB, hAll, hBf, s);
        }
    }
    projK<<<FLAT / 256, 256, 0, stream>>>(Wproj, bproj, hBf, out);
}

// Round 3
// 921.561 us; speedup vs baseline: 2.5178x; 2.5178x over previous
//
#include <hip/hip_runtime.h>
#include <hip/hip_bf16.h>
#include <math.h>

typedef __bf16 bf16x8 __attribute__((ext_vector_type(8)));
typedef float  f32x4  __attribute__((ext_vector_type(4)));

#define HDIM   512
#define FLAT   65792
#define DIN    66304
#define G3     1536          // 3*H
#define NSLAB  2056          // FLAT / 32
#define NPAD   576           // padded GEMM N: 512 (M) + b_proj + start + 62 zero (div by 64)
#define LPITCH 40            // LDS row pitch in ushorts (80 B)
#define MT     128           // GEMM M tile
#define KSPLIT 21
#define CHUNK  98            // slabs per K chunk (21*98 >= 2056)
#define SLABU  18432         // ushorts per Bh slab = NPAD*32

#define BH_BYTES  75792384ULL   // NSLAB * SLABU * 2
#define MBUF_BYTES 3538944ULL   // G3*NPAD*4
#define GIB_BYTES   393216ULL   // 64*G3*4
#define HALL_BYTES  131072ULL   // 64*512*4
#define HBF_BYTES    65536ULL   // 64*512*2

__device__ __forceinline__ ushort f2bf(float f) {
    uint u = __float_as_uint(f);
    u += 0x7FFFu + ((u >> 16) & 1u);   // round-to-nearest-even
    return (ushort)(u >> 16);
}

// ---------------------------------------------------------------------------
// K1 (fast path): build blocked bf16 B matrix for the big GEMM.
// Bh[slab][n][kk] = B[k = slab*32+kk][n], n<512: W_proj[k][n], 512: b_proj[k],
// 513: start_token[k], 514..575: 0.
// ---------------------------------------------------------------------------
__global__ __launch_bounds__(256) void buildBh(const float* __restrict__ Wp,
                                               const float* __restrict__ bproj,
                                               const float* __restrict__ start,
                                               ushort* __restrict__ Bh) {
    __shared__ ushort tr[512 * 33];
    const int slab = blockIdx.x;
    const int tid  = threadIdx.x;
    for (int idx = tid; idx < 32 * 512; idx += 256) {
        const int k = idx >> 9;
        const int n = idx & 511;
        tr[n * 33 + k] = f2bf(Wp[(size_t)(slab * 32 + k) * 512 + n]);
    }
    __syncthreads();
    uint* out = (uint*)(Bh + (size_t)slab * SLABU);
    for (int d = tid; d < (SLABU / 2); d += 256) {
        const int n  = d >> 4;
        const int k2 = (d & 15) * 2;
        ushort lo, hi;
        if (n < 512)      { lo = tr[n * 33 + k2];            hi = tr[n * 33 + k2 + 1]; }
        else if (n == 512){ lo = f2bf(bproj[slab * 32 + k2]); hi = f2bf(bproj[slab * 32 + k2 + 1]); }
        else if (n == 513){ lo = f2bf(start[slab * 32 + k2]); hi = f2bf(start[slab * 32 + k2 + 1]); }
        else              { lo = 0; hi = 0; }
        out[d] = (uint)lo | ((uint)hi << 16);
    }
}

// ---------------------------------------------------------------------------
// K2 (fast path): M = W_ih[:,512:] @ [W_proj | b_proj | start | 0pad] (1536x576)
// split-K, bf16 MFMA 16x16x32, fp32 atomicAdd accumulation into Mbuf.
// Wave grid 4Mx4N: each wave owns 2 M-frags x 9 N-frags -> 11 ds_read_b128
// per slab for 18 MFMA (was 18 reads / 17 MFMA) -> LDS-read cycles -40%.
// ---------------------------------------------------------------------------
__global__ __launch_bounds__(1024) void gemmM(const float* __restrict__ Wih,
                                              const ushort* __restrict__ Bh,
                                              float* __restrict__ Mbuf) {
    __shared__ ushort Alds[MT * LPITCH];       // 10240 B
    __shared__ ushort Blds[NPAD * LPITCH];     // 46080 B
    const int tid  = threadIdx.x;
    const int lane = tid & 63;
    const int wave = tid >> 6;
    const int wm2  = wave >> 2;       // 0..3 -> rows wm2*32
    const int wn2  = wave & 3;        // 0..3 -> cols wn2*144
    const int lrow = lane & 15;
    const int quad = lane >> 4;
    const int bid   = blockIdx.x;
    const int mtile = bid % 12;
    const int kc    = bid / 12;
    const int s0 = kc * CHUNK;
    const int s1 = min(s0 + CHUNK, NSLAB);

    const int arow = tid >> 3;
    const int aseg = tid & 7;
    const float* aPtr = Wih + (size_t)(mtile * MT + arow) * DIN + 512 + aseg * 4;

    f32x4 acc[2][9];
#pragma unroll
    for (int p = 0; p < 2; ++p)
#pragma unroll
        for (int t = 0; t < 9; ++t) acc[p][t] = (f32x4){0.f, 0.f, 0.f, 0.f};

    float4 aReg;
    uint4  bReg0 = {}, bReg1 = {}, bReg2 = {};
    {
        const size_t sb = (size_t)s0 * SLABU;
        aReg  = *(const float4*)(aPtr + (size_t)s0 * 32);
        bReg0 = *(const uint4*)(Bh + sb + (size_t)tid * 8);
        bReg1 = *(const uint4*)(Bh + sb + (size_t)(tid + 1024) * 8);
        if (tid < 256) bReg2 = *(const uint4*)(Bh + sb + (size_t)(tid + 2048) * 8);
    }
    for (int s = s0; s < s1; ++s) {
        {
            uint2 ap;
            ap.x = (uint)f2bf(aReg.x) | ((uint)f2bf(aReg.y) << 16);
            ap.y = (uint)f2bf(aReg.z) | ((uint)f2bf(aReg.w) << 16);
            *(uint2*)&Alds[arow * LPITCH + aseg * 4] = ap;
            *(uint4*)&Blds[(tid >> 2) * LPITCH + (tid & 3) * 8] = bReg0;
            const int c1 = tid + 1024;
            *(uint4*)&Blds[(c1 >> 2) * LPITCH + (c1 & 3) * 8] = bReg1;
            if (tid < 256) {
                const int c2 = tid + 2048;
                *(uint4*)&Blds[(c2 >> 2) * LPITCH + (c2 & 3) * 8] = bReg2;
            }
        }
        __syncthreads();
        if (s + 1 < s1) {
            const size_t sb = (size_t)(s + 1) * SLABU;
            aReg  = *(const float4*)(aPtr + (size_t)(s + 1) * 32);
            bReg0 = *(const uint4*)(Bh + sb + (size_t)tid * 8);
            bReg1 = *(const uint4*)(Bh + sb + (size_t)(tid + 1024) * 8);
            if (tid < 256) bReg2 = *(const uint4*)(Bh + sb + (size_t)(tid + 2048) * 8);
        }
        bf16x8 af[2];
#pragma unroll
        for (int p = 0; p < 2; ++p)
            af[p] = __builtin_bit_cast(bf16x8,
                *(const uint4*)&Alds[(wm2 * 32 + p * 16 + lrow) * LPITCH + quad * 8]);
#pragma unroll
        for (int t = 0; t < 9; ++t) {
            const bf16x8 bf = __builtin_bit_cast(bf16x8,
                *(const uint4*)&Blds[(wn2 * 144 + t * 16 + lrow) * LPITCH + quad * 8]);
            acc[0][t] = __builtin_amdgcn_mfma_f32_16x16x32_bf16(af[0], bf, acc[0][t], 0, 0, 0);
            acc[1][t] = __builtin_amdgcn_mfma_f32_16x16x32_bf16(af[1], bf, acc[1][t], 0, 0, 0);
        }
        __syncthreads();
    }
#pragma unroll
    for (int p = 0; p < 2; ++p)
#pragma unroll
        for (int t = 0; t < 9; ++t) {
            const int col = wn2 * 144 + t * 16 + lrow;
#pragma unroll
            for (int r = 0; r < 4; ++r) {
                const int row = mtile * MT + wm2 * 32 + p * 16 + quad * 4 + r;
                atomicAdd(&Mbuf[(size_t)row * NPAD + col], acc[p][t][r]);
            }
        }
}

// ---------------------------------------------------------------------------
// K2' (fallback, small ws_size): same GEMM but reads W_proj fp32 directly and
// transposes in-LDS per slab. Same 4Mx4N wave grid.
// ---------------------------------------------------------------------------
__global__ __launch_bounds__(1024) void gemmMDirect(const float* __restrict__ Wih,
                                                    const float* __restrict__ Wp,
                                                    const float* __restrict__ bproj,
                                                    const float* __restrict__ start,
                                                    float* __restrict__ Mbuf) {
    __shared__ ushort Alds[MT * LPITCH];
    __shared__ ushort Blds[NPAD * LPITCH];
    const int tid  = threadIdx.x;
    const int lane = tid & 63;
    const int wave = tid >> 6;
    const int wm2  = wave >> 2;
    const int wn2  = wave & 3;
    const int lrow = lane & 15;
    const int quad = lane >> 4;
    const int bid   = blockIdx.x;
    const int mtile = bid % 12;
    const int kc    = bid / 12;
    const int s0 = kc * CHUNK;
    const int s1 = min(s0 + CHUNK, NSLAB);

    const int arow = tid >> 3;
    const int aseg = tid & 7;
    const float* aPtr = Wih + (size_t)(mtile * MT + arow) * DIN + 512 + aseg * 4;

    const int bk  = tid >> 5;
    const int bn0 = (tid & 31) * 4;
    const int ek  = tid & 31;
    const float* esrc = (tid < 32) ? bproj : start;

    // zero pad rows 514..575 once (never overwritten afterwards)
    for (int idx = tid; idx < 62 * LPITCH; idx += 1024) Blds[514 * LPITCH + idx] = 0;

    f32x4 acc[2][9];
#pragma unroll
    for (int p = 0; p < 2; ++p)
#pragma unroll
        for (int t = 0; t < 9; ++t) acc[p][t] = (f32x4){0.f, 0.f, 0.f, 0.f};

    float4 aReg;
    float4 bReg[4];
    float  eReg = 0.f;
    {
        aReg = *(const float4*)(aPtr + (size_t)s0 * 32);
        const float* bbase = Wp + (size_t)(s0 * 32 + bk) * 512 + bn0;
#pragma unroll
        for (int q = 0; q < 4; ++q) bReg[q] = *(const float4*)(bbase + q * 128);
        if (tid < 64) eReg = esrc[s0 * 32 + ek];
    }
    for (int s = s0; s < s1; ++s) {
        {
            uint2 ap;
            ap.x = (uint)f2bf(aReg.x) | ((uint)f2bf(aReg.y) << 16);
            ap.y = (uint)f2bf(aReg.z) | ((uint)f2bf(aReg.w) << 16);
            *(uint2*)&Alds[arow * LPITCH + aseg * 4] = ap;
#pragma unroll
            for (int q = 0; q < 4; ++q) {
                const int n = bn0 + q * 128;
                Blds[(n + 0) * LPITCH + bk] = f2bf(bReg[q].x);
                Blds[(n + 1) * LPITCH + bk] = f2bf(bReg[q].y);
                Blds[(n + 2) * LPITCH + bk] = f2bf(bReg[q].z);
                Blds[(n + 3) * LPITCH + bk] = f2bf(bReg[q].w);
            }
            if (tid < 64) Blds[(512 + (tid >> 5)) * LPITCH + ek] = f2bf(eReg);
        }
        __syncthreads();
        if (s + 1 < s1) {
            aReg = *(const float4*)(aPtr + (size_t)(s + 1) * 32);
            const float* bbase = Wp + (size_t)((s + 1) * 32 + bk) * 512 + bn0;
#pragma unroll
            for (int q = 0; q < 4; ++q) bReg[q] = *(const float4*)(bbase + q * 128);
            if (tid < 64) eReg = esrc[(s + 1) * 32 + ek];
        }
        bf16x8 af[2];
#pragma unroll
        for (int p = 0; p < 2; ++p)
            af[p] = __builtin_bit_cast(bf16x8,
                *(const uint4*)&Alds[(wm2 * 32 + p * 16 + lrow) * LPITCH + quad * 8]);
#pragma unroll
        for (int t = 0; t < 9; ++t) {
            const bf16x8 bf = __builtin_bit_cast(bf16x8,
                *(const uint4*)&Blds[(wn2 * 144 + t * 16 + lrow) * LPITCH + quad * 8]);
            acc[0][t] = __builtin_amdgcn_mfma_f32_16x16x32_bf16(af[0], bf, acc[0][t], 0, 0, 0);
            acc[1][t] = __builtin_amdgcn_mfma_f32_16x16x32_bf16(af[1], bf, acc[1][t], 0, 0, 0);
        }
        __syncthreads();
    }
#pragma unroll
    for (int p = 0; p < 2; ++p)
#pragma unroll
        for (int t = 0; t < 9; ++t) {
            const int col = wn2 * 144 + t * 16 + lrow;
#pragma unroll
            for (int r = 0; r < 4; ++r) {
                const int row = mtile * MT + wm2 * 32 + p * 16 + quad * 4 + r;
                atomicAdd(&Mbuf[(size_t)row * NPAD + col], acc[p][t][r]);
            }
        }
}

// ---------------------------------------------------------------------------
// K3: gi_base[pair][j] = b_ih[j] + W_ih[j,:256]@content[b,s] + W_ih[j,256:512]@style[b]
//                        + (s==0 ? (A@start)[j] : (A@b_proj)[j])
// ---------------------------------------------------------------------------
__global__ __launch_bounds__(256) void giBase(const float* __restrict__ Wih,
                                              const float* __restrict__ content,
                                              const float* __restrict__ style,
                                              const float* __restrict__ bih,
                                              const float* __restrict__ Mbuf,
                                              float* __restrict__ giB) {
    const int j = (blockIdx.x * blockDim.x + threadIdx.x) >> 6;
    if (j >= G3) return;
    const int lane = threadIdx.x & 63;   // pair = b*16 + s
    const int b = lane >> 4;
    const int s = lane & 15;
    const float* wr = Wih + (size_t)j * DIN;
    const float* cp = content + (size_t)lane * 256;
    const float* sp = style + (size_t)b * 256;
    float acc = 0.f;
#pragma unroll 4
    for (int d = 0; d < 256; d += 4) {
        const float4 w = *(const float4*)(wr + d);
        const float4 x = *(const float4*)(cp + d);
        acc += w.x * x.x + w.y * x.y + w.z * x.z + w.w * x.w;
    }
#pragma unroll 4
    for (int d = 0; d < 256; d += 4) {
        const float4 w = *(const float4*)(wr + 256 + d);
        const float4 x = *(const float4*)(sp + d);
        acc += w.x * x.x + w.y * x.y + w.z * x.z + w.w * x.w;
    }
    acc += bih[j] + ((s == 0) ? Mbuf[(size_t)j * NPAD + 513] : Mbuf[(size_t)j * NPAD + 512]);
    giB[(size_t)lane * G3 + j] = acc;
}

// ---------------------------------------------------------------------------
// K4 (x16): one GRU step. Wave per (b, j): six 512-length dots, shuffle-reduce.
// (16 separate launches ~7 us each; cooperative grid.sync measured 94 us/sync
//  on this chip -> fused variant removed.)
// ---------------------------------------------------------------------------
__global__ __launch_bounds__(256) void stepK(const float* __restrict__ Mbuf,
                                             const float* __restrict__ Whh,
                                             const float* __restrict__ bhh,
                                             const float* __restrict__ giB,
                                             float* __restrict__ hAll,
                                             ushort* __restrict__ hBf,
                                             const int s) {
    const int gw   = (blockIdx.x * blockDim.x + threadIdx.x) >> 6;  // 0..2047
    const int lane = threadIdx.x & 63;
    const int b = gw & 3;
    const int j = gw >> 2;          // 0..511
    float dMr = 0.f, dMz = 0.f, dMn = 0.f, dWr = 0.f, dWz = 0.f, dWn = 0.f;
    if (s > 0) {
        const float* h = hAll + (size_t)((s - 1) * 4 + b) * HDIM;
        float hr[8];
#pragma unroll
        for (int i = 0; i < 8; ++i) hr[i] = h[i * 64 + lane];
        const float* M0 = Mbuf + (size_t)j * NPAD;
        const float* M1 = Mbuf + (size_t)(j + 512) * NPAD;
        const float* M2 = Mbuf + (size_t)(j + 1024) * NPAD;
        const float* W0 = Whh + (size_t)j * HDIM;
        const float* W1 = Whh + (size_t)(j + 512) * HDIM;
        const float* W2 = Whh + (size_t)(j + 1024) * HDIM;
#pragma unroll
        for (int i = 0; i < 8; ++i) {
            const int d = i * 64 + lane;
            dMr += M0[d] * hr[i]; dMz += M1[d] * hr[i]; dMn += M2[d] * hr[i];
            dWr += W0[d] * hr[i]; dWz += W1[d] * hr[i]; dWn += W2[d] * hr[i];
        }
#pragma unroll
        for (int m = 1; m < 64; m <<= 1) {
            dMr += __shfl_xor(dMr, m); dMz += __shfl_xor(dMz, m); dMn += __shfl_xor(dMn, m);
            dWr += __shfl_xor(dWr, m); dWz += __shfl_xor(dWz, m); dWn += __shfl_xor(dWn, m);
        }
    }
    if (lane == 0) {
        const float* gb = giB + (size_t)(b * 16 + s) * G3;
        const float gir = gb[j] + dMr;
        const float giz = gb[j + 512] + dMz;
        const float gin = gb[j + 1024] + dMn;
        const float ghr = bhh[j] + dWr;
        const float ghz = bhh[j + 512] + dWz;
        const float ghn = bhh[j + 1024] + dWn;
        const float r = 1.f / (1.f + expf(-(gir + ghr)));
        const float z = 1.f / (1.f + expf(-(giz + ghz)));
        const float n = tanhf(gin + r * ghn);
        const float hp = (s > 0) ? hAll[(size_t)((s - 1) * 4 + b) * HDIM + j] : 0.f;
        const float hn = (1.f - z) * n + z * hp;
        hAll[(size_t)(s * 4 + b) * HDIM + j] = hn;
        hBf[(size_t)(s * 4 + b) * HDIM + j] = f2bf(hn);
    }
}

// ---------------------------------------------------------------------------
// K5: out[b][s][f] = W_proj[f] . h[s*4+b] + b_proj[f], MFMA bf16.
// ---------------------------------------------------------------------------
__global__ __launch_bounds__(256) void projK(const float* __restrict__ Wp,
                                             const float* __restrict__ bproj,
                                             const ushort* __restrict__ hBf,
                                             float* __restrict__ out) {
    const int lane = threadIdx.x & 63;
    const int wave = threadIdx.x >> 6;
    const int f0   = blockIdx.x * 256 + wave * 64;
    const int lrow = lane & 15;
    const int quad = lane >> 4;
    f32x4 acc[4][4];
#pragma unroll
    for (int pt = 0; pt < 4; ++pt)
#pragma unroll
        for (int ft = 0; ft < 4; ++ft) acc[pt][ft] = (f32x4){0.f, 0.f, 0.f, 0.f};

    for (int d0 = 0; d0 < HDIM; d0 += 32) {
        bf16x8 afr[4];
#pragma unroll
        for (int pt = 0; pt < 4; ++pt)
            afr[pt] = __builtin_bit_cast(bf16x8,
                *(const uint4*)(hBf + (size_t)(pt * 16 + lrow) * HDIM + d0 + quad * 8));
#pragma unroll
        for (int ft = 0; ft < 4; ++ft) {
            const float* wrow = Wp + (size_t)(f0 + ft * 16 + lrow) * HDIM + d0 + quad * 8;
            const float4 w0 = *(const float4*)(wrow);
            const float4 w1 = *(const float4*)(wrow + 4);
            uint4 pr;
            pr.x = (uint)f2bf(w0.x) | ((uint)f2bf(w0.y) << 16);
            pr.y = (uint)f2bf(w0.z) | ((uint)f2bf(w0.w) << 16);
            pr.z = (uint)f2bf(w1.x) | ((uint)f2bf(w1.y) << 16);
            pr.w = (uint)f2bf(w1.z) | ((uint)f2bf(w1.w) << 16);
            const bf16x8 bfr = __builtin_bit_cast(bf16x8, pr);
#pragma unroll
            for (int pt = 0; pt < 4; ++pt)
                acc[pt][ft] = __builtin_amdgcn_mfma_f32_16x16x32_bf16(afr[pt], bfr, acc[pt][ft], 0, 0, 0);
        }
    }
#pragma unroll
    for (int pt = 0; pt < 4; ++pt)
#pragma unroll
        for (int ft = 0; ft < 4; ++ft) {
            const int f = f0 + ft * 16 + lrow;
            const float bp = bproj[f];
#pragma unroll
            for (int r = 0; r < 4; ++r) {
                const int p = pt * 16 + quad * 4 + r;   // pair index = s*4 + b
                const int ss = p >> 2;
                const int bb = p & 3;
                out[(size_t)(bb * 16 + ss) * FLAT + f] = acc[pt][ft][r] + bp;
            }
        }
}

// ---------------------------------------------------------------------------
extern "C" void kernel_launch(void* const* d_in, const int* in_sizes, int n_in,
                              void* d_out, int out_size, void* d_ws, size_t ws_size,
                              hipStream_t stream) {
    const float* content = (const float*)d_in[0];  // (4,16,256)
    const float* style   = (const float*)d_in[1];  // (4,256)
    const float* start   = (const float*)d_in[2];  // (65792)
    const float* Wih     = (const float*)d_in[3];  // (1536, 66304)
    const float* Whh     = (const float*)d_in[4];  // (1536, 512)
    const float* bih     = (const float*)d_in[5];  // (1536)
    const float* bhh     = (const float*)d_in[6];  // (1536)
    const float* Wproj   = (const float*)d_in[7];  // (65792, 512)
    const float* bproj   = (const float*)d_in[8];  // (65792)
    float* out = (float*)d_out;

    const size_t needFast = BH_BYTES + MBUF_BYTES + GIB_BYTES + HALL_BYTES + HBF_BYTES;
    const bool fast = (ws_size >= needFast);   // constant per deployment -> graph-safe

    char* ws = (char*)d_ws;
    const size_t base = fast ? BH_BYTES : 0;
    ushort* Bh   = (ushort*)ws;
    float*  Mbuf = (float*)(ws + base);
    float*  giB  = (float*)(ws + base + MBUF_BYTES);
    float*  hAll = (float*)(ws + base + MBUF_BYTES + GIB_BYTES);
    ushort* hBf  = (ushort*)(ws + base + MBUF_BYTES + GIB_BYTES + HALL_BYTES);

    hipMemsetAsync(Mbuf, 0, MBUF_BYTES, stream);
    if (fast) {
        buildBh<<<NSLAB, 256, 0, stream>>>(Wproj, bproj, start, Bh);
        gemmM<<<12 * KSPLIT, 1024, 0, stream>>>(Wih, Bh, Mbuf);
    } else {
        gemmMDirect<<<12 * KSPLIT, 1024, 0, stream>>>(Wih, Wproj, bproj, start, Mbuf);
    }
    giBase<<<384, 256, 0, stream>>>(Wih, content, style, bih, Mbuf, giB);
    for (int s = 0; s < 16; ++s)
        stepK<<<512, 256, 0, stream>>>(Mbuf, Whh, bhh, giB, hAll, hBf, s);
    projK<<<FLAT / 256, 256, 0, stream>>>(Wproj, bproj, hBf, out);
}